// Round 5
// baseline (146.298 us; speedup 1.0000x reference)
//
#include <hip/hip_runtime.h>

typedef __bf16 bf16;
typedef __bf16 bf16x4 __attribute__((ext_vector_type(4)));
typedef __bf16 bf16x8 __attribute__((ext_vector_type(8)));
typedef float  f32x4  __attribute__((ext_vector_type(4)));

#define CIN   256
#define KK    9
#define KDIM  2304
#define KITERS 72            // KDIM / 32
#define PXW   32             // pixels per WG
#define SROW  264            // 256 + 8 bf16 pad

// force a wave-uniform value into an SGPR
__device__ __forceinline__ float sread(float f) {
    return __builtin_bit_cast(float,
        __builtin_amdgcn_readfirstlane(__builtin_bit_cast(int, f)));
}
__device__ __forceinline__ int sreadi(int v) {
    return __builtin_amdgcn_readfirstlane(v);
}

// ---------------------------------------------------------------------------
// Fused prep: blocks [0,1024) transpose x -> channels-last bf16 xt;
//             blocks [1024,3328) pack weight -> MFMA-fragment-ordered wq:
//   wq[ ((m*72 + kt)*64 + lane)*8 + j ] = W[o=m*16+l16][k=kt*32+quad*8+j]
//   k -> (tap = k>>8, c = k&255);  lane = quad*16+l16.
// ---------------------------------------------------------------------------
__global__ __launch_bounds__(256) void prep_k(const float* __restrict__ x,
                                              const float* __restrict__ w,
                                              bf16* __restrict__ xt,
                                              bf16* __restrict__ wq) {
    int bid = blockIdx.x;
    int tid = threadIdx.x;
    if (bid < 1024) {
        __shared__ bf16 tile[64][72];        // px-major; rows 144 B
        int pt = bid & 63, ct = (bid >> 6) & 3, b = bid >> 8;
        int lane = tid & 63, row = tid >> 6;
        const float* src = x + ((size_t)(b * 256 + ct * 64)) * 4096 + pt * 64;
        #pragma unroll
        for (int cc = row; cc < 64; cc += 4)
            tile[lane][cc] = (bf16)src[(size_t)cc * 4096 + lane];
        __syncthreads();
        bf16* dst = xt + ((size_t)(b * 4096 + pt * 64)) * 256 + ct * 64;
        int p = tid >> 3, j = tid & 7;
        #pragma unroll
        for (int pp = p; pp < 64; pp += 32)
            *reinterpret_cast<bf16x8*>(dst + (size_t)pp * 256 + j * 8) =
                *reinterpret_cast<const bf16x8*>(&tile[pp][j * 8]);
    } else {
        int idx  = (bid - 1024) * 256 + tid;   // < 589824
        int j    = idx & 7;
        int lane = (idx >> 3) & 63;
        int rest = idx >> 9;                   // m*72 + kt
        int kt   = rest % KITERS;
        int m    = rest / KITERS;
        int l16  = lane & 15;
        int quad = lane >> 4;
        int o    = m * 16 + l16;
        int k    = kt * 32 + quad * 8 + j;
        int tap  = k >> 8;
        int cc   = k & 255;
        wq[idx] = (bf16)w[(size_t)o * KDIM + cc * KK + tap];
    }
}

// ---------------------------------------------------------------------------
// Fused sampling -> LDS -> MFMA GEMM
// WG = 256 thr (4 waves), 32 pixels. Wave = M64 (4 mtiles) x N32 (2 ntiles).
// Grid 512; launch_bounds(256,6) -> target 6 WGs/CU = 24 waves/CU (75% occ).
// XCD-band swizzle: blocks with bid%8==x form one contiguous 2048-px band,
// so each XCD's xt gathers (~1.1 MB) + weights (1.18 MB) stay in its 4 MB L2.
// ---------------------------------------------------------------------------
__global__ __launch_bounds__(256, 6) void deform_gemm_k(
    const bf16*  __restrict__ xt,
    const float* __restrict__ off,
    const bf16*  __restrict__ wq,
    const float* __restrict__ bias,
    float*       __restrict__ out) {

    __shared__ bf16 S[PXW][SROW];   // 16,896 B

    int tid   = threadIdx.x;
    int wavei = sreadi(tid >> 6);   // 0..3, compiler-known wave-uniform
    int lane  = tid & 63;
    int quad  = lane >> 4;
    int l16   = lane & 15;

    int bid   = blockIdx.x;                      // 0..511
    int pb    = ((bid & 7) << 6) | (bid >> 3);   // XCD-band pixel-block
    int pix0  = pb * PXW;
    int b     = pix0 >> 12;                      // WG-uniform batch
    int pimgb = pix0 & 4095;
    int obase = b * 73728;                       // scalar base into off[]
    unsigned base = (unsigned)b * 1048576u + (unsigned)(lane * 4); // into xt[]

    f32x4 acc[4][2];
    #pragma unroll
    for (int mt = 0; mt < 4; ++mt)
        #pragma unroll
        for (int nt = 0; nt < 2; ++nt)
            acc[mt][nt] = (f32x4){0.f, 0.f, 0.f, 0.f};

    for (int tap = 0; tap < KK; ++tap) {
        int ty = tap / 3 - 1;
        int tx = tap % 3 - 1;

        // ---- sampling: wave fills rows wavei*8 .. wavei*8+7, 2 groups of 4 ----
        #pragma unroll
        for (int g = 0; g < 2; ++g) {
            int u[4][4];        // scalar (SGPR) element offsets within batch image
            float wt[4][4];     // scalar (SGPR) bilinear weights
            #pragma unroll
            for (int i = 0; i < 4; ++i) {
                int n    = wavei * 8 + g * 4 + i;
                int pimg = pimgb + n;                      // scalar
                float oy = off[obase + pimg + (2 * tap) * 4096];      // s_load
                float ox = off[obase + pimg + (2 * tap + 1) * 4096];  // s_load
                float py = (float)((pimg >> 6) + ty) + oy;
                float px = (float)((pimg & 63) + tx) + ox;
                float fy = floorf(py), fx = floorf(px);
                int   y0 = (int)fy,    x0 = (int)fx;
                float wy1 = py - fy, wx1 = px - fx;
                float wy0 = 1.f - wy1, wx0 = 1.f - wx1;
                wy0 = ((unsigned)y0       < 64u) ? wy0 : 0.f;
                wy1 = ((unsigned)(y0 + 1) < 64u) ? wy1 : 0.f;
                wx0 = ((unsigned)x0       < 64u) ? wx0 : 0.f;
                wx1 = ((unsigned)(x0 + 1) < 64u) ? wx1 : 0.f;
                int yc0 = min(max(y0, 0), 63),     yc1 = min(max(y0 + 1, 0), 63);
                int xc0 = min(max(x0, 0), 63),     xc1 = min(max(x0 + 1, 0), 63);
                u[i][0] = sreadi((yc0 * 64 + xc0) * 256);
                u[i][1] = sreadi((yc0 * 64 + xc1) * 256);
                u[i][2] = sreadi((yc1 * 64 + xc0) * 256);
                u[i][3] = sreadi((yc1 * 64 + xc1) * 256);
                wt[i][0] = sread(wy0 * wx0); wt[i][1] = sread(wy0 * wx1);
                wt[i][2] = sread(wy1 * wx0); wt[i][3] = sread(wy1 * wx1);
            }
            // issue all 16 gathers back-to-back (L2-local after band swizzle)
            bf16x4 v[4][4];
            #pragma unroll
            for (int i = 0; i < 4; ++i)
                #pragma unroll
                for (int j = 0; j < 4; ++j)
                    v[i][j] = *reinterpret_cast<const bf16x4*>(xt + base + (unsigned)u[i][j]);
            // blend + LDS write
            #pragma unroll
            for (int i = 0; i < 4; ++i) {
                float a0 = 0.f, a1 = 0.f, a2 = 0.f, a3 = 0.f;
                #pragma unroll
                for (int j = 0; j < 4; ++j) {
                    float wgt = wt[i][j];
                    a0 += wgt * (float)v[i][j][0];
                    a1 += wgt * (float)v[i][j][1];
                    a2 += wgt * (float)v[i][j][2];
                    a3 += wgt * (float)v[i][j][3];
                }
                bf16x4 sv;
                sv[0] = (bf16)a0; sv[1] = (bf16)a1;
                sv[2] = (bf16)a2; sv[3] = (bf16)a3;
                *reinterpret_cast<bf16x4*>(&S[wavei * 8 + g * 4 + i][lane * 4]) = sv;
            }
        }
        __syncthreads();

        // ---- GEMM over this tap's k=256: wave = M64 x N32 ----
        const bf16* sp0 = &S[l16][quad * 8];
        const bf16* sp1 = &S[16 + l16][quad * 8];
        #pragma unroll
        for (int kki = 0; kki < 8; ++kki) {
            bf16x8 b0 = *reinterpret_cast<const bf16x8*>(sp0 + kki * 32);
            bf16x8 b1 = *reinterpret_cast<const bf16x8*>(sp1 + kki * 32);
            #pragma unroll
            for (int mt = 0; mt < 4; ++mt) {
                const bf16* ap = wq +
                    ((size_t)(((wavei * 4 + mt) * KITERS + tap * 8 + kki) * 64 + lane)) * 8;
                bf16x8 a = *reinterpret_cast<const bf16x8*>(ap);
                acc[mt][0] = __builtin_amdgcn_mfma_f32_16x16x32_bf16(a, b0, acc[mt][0], 0, 0, 0);
                acc[mt][1] = __builtin_amdgcn_mfma_f32_16x16x32_bf16(a, b1, acc[mt][1], 0, 0, 0);
            }
        }
        __syncthreads();   // S reused next tap
    }

    // ---- epilogue: C/D layout col=l16, row=quad*4+r ----
    #pragma unroll
    for (int nt = 0; nt < 2; ++nt) {
        int pg   = pix0 + nt * 16 + l16;
        int bb   = pg >> 12;
        int pimg = pg & 4095;
        #pragma unroll
        for (int mt = 0; mt < 4; ++mt) {
            int m = (wavei * 4 + mt) * 16 + quad * 4;
            float* op = out + ((size_t)(bb * 256 + m)) * 4096 + pimg;
            #pragma unroll
            for (int r = 0; r < 4; ++r)
                op[(size_t)r * 4096] = acc[mt][nt][r] + bias[m + r];
        }
    }
}

// ---------------------------------------------------------------------------
extern "C" void kernel_launch(void* const* d_in, const int* in_sizes, int n_in,
                              void* d_out, int out_size, void* d_ws, size_t ws_size,
                              hipStream_t stream) {
    const float* x    = (const float*)d_in[0];   // [4,256,64,64]
    const float* off  = (const float*)d_in[1];   // [4,18,64,64]
    const float* w    = (const float*)d_in[2];   // [256,256,3,3]
    const float* bias = (const float*)d_in[3];   // [256]
    float* out = (float*)d_out;                  // [4,256,64,64]

    bf16* wq = (bf16*)d_ws;                               // 1,179,648 B
    bf16* xt = (bf16*)((char*)d_ws + (size_t)589824 * 2); // 8,388,608 B

    prep_k<<<3328, 256, 0, stream>>>(x, w, xt, wq);
    deform_gemm_k<<<512, 256, 0, stream>>>(xt, off, wq, bias, out);
}

// Round 6
// 119.939 us; speedup vs baseline: 1.2198x; 1.2198x over previous
//
#include <hip/hip_runtime.h>

typedef __bf16 bf16;
typedef __bf16 bf16x4 __attribute__((ext_vector_type(4)));
typedef __bf16 bf16x8 __attribute__((ext_vector_type(8)));
typedef float  f32x4  __attribute__((ext_vector_type(4)));

#define CIN   256
#define KK    9
#define KDIM  2304
#define KITERS 72            // KDIM / 32
#define PXW   32             // pixels per WG
#define SROW  264            // 256 + 8 bf16 pad

// force a wave-uniform value into an SGPR
__device__ __forceinline__ float sread(float f) {
    return __builtin_bit_cast(float,
        __builtin_amdgcn_readfirstlane(__builtin_bit_cast(int, f)));
}
__device__ __forceinline__ int sreadi(int v) {
    return __builtin_amdgcn_readfirstlane(v);
}

// ---------------------------------------------------------------------------
// Fused prep: blocks [0,1024) transpose x -> channels-last bf16 xt;
//             blocks [1024,3328) pack weight -> MFMA-fragment-ordered wq:
//   wq[ ((m*72 + kt)*64 + lane)*8 + j ] = W[o=m*16+l16][k=kt*32+quad*8+j]
//   k -> (tap = k>>8, c = k&255);  lane = quad*16+l16.
// ---------------------------------------------------------------------------
__global__ __launch_bounds__(256) void prep_k(const float* __restrict__ x,
                                              const float* __restrict__ w,
                                              bf16* __restrict__ xt,
                                              bf16* __restrict__ wq) {
    int bid = blockIdx.x;
    int tid = threadIdx.x;
    if (bid < 1024) {
        __shared__ bf16 tile[64][72];        // px-major; rows 144 B
        int pt = bid & 63, ct = (bid >> 6) & 3, b = bid >> 8;
        int lane = tid & 63, row = tid >> 6;
        const float* src = x + ((size_t)(b * 256 + ct * 64)) * 4096 + pt * 64;
        #pragma unroll
        for (int cc = row; cc < 64; cc += 4)
            tile[lane][cc] = (bf16)src[(size_t)cc * 4096 + lane];
        __syncthreads();
        bf16* dst = xt + ((size_t)(b * 4096 + pt * 64)) * 256 + ct * 64;
        int p = tid >> 3, j = tid & 7;
        #pragma unroll
        for (int pp = p; pp < 64; pp += 32)
            *reinterpret_cast<bf16x8*>(dst + (size_t)pp * 256 + j * 8) =
                *reinterpret_cast<const bf16x8*>(&tile[pp][j * 8]);
    } else {
        int idx  = (bid - 1024) * 256 + tid;   // < 589824
        int j    = idx & 7;
        int lane = (idx >> 3) & 63;
        int rest = idx >> 9;                   // m*72 + kt
        int kt   = rest % KITERS;
        int m    = rest / KITERS;
        int l16  = lane & 15;
        int quad = lane >> 4;
        int o    = m * 16 + l16;
        int k    = kt * 32 + quad * 8 + j;
        int tap  = k >> 8;
        int cc   = k & 255;
        wq[idx] = (bf16)w[(size_t)o * KDIM + cc * KK + tap];
    }
}

// ---------------------------------------------------------------------------
// Fused sampling -> LDS -> MFMA GEMM
// WG = 512 thr (8 waves), 32 pixels. Wave = M32 (2 mtiles) x N32 (2 ntiles).
// Grid 512 -> 2 WGs/CU = 16 waves/CU (50% occupancy cap).
// XCD band swizzle: bid%8 selects XCD-contiguous 2048-px band so each XCD's
// gathers (~1.1 MB) + weights (1.18 MB) live in its 4 MB L2
// (round 5 evidence: FETCH_SIZE 33.5 -> 10.3 MB).
// Sampling math is wave-uniform -> SGPRs via readfirstlane; offset reads are
// scalar loads.
// ---------------------------------------------------------------------------
__global__ __launch_bounds__(512, 4) void deform_gemm_k(
    const bf16*  __restrict__ xt,
    const float* __restrict__ off,
    const bf16*  __restrict__ wq,
    const float* __restrict__ bias,
    float*       __restrict__ out) {

    __shared__ bf16 S[PXW][SROW];   // 16,896 B

    int tid   = threadIdx.x;
    int wavei = sreadi(tid >> 6);   // 0..7
    int lane  = tid & 63;
    int quad  = lane >> 4;
    int l16   = lane & 15;

    int bid   = blockIdx.x;                      // 0..511
    int pb    = ((bid & 7) << 6) | (bid >> 3);   // XCD-band pixel-block
    int pix0  = pb * PXW;
    int b     = pix0 >> 12;                      // WG-uniform batch
    int pimgb = pix0 & 4095;
    int obase = b * 73728;                       // scalar base into off[]
    unsigned base = (unsigned)b * 1048576u + (unsigned)(lane * 4); // into xt[]

    f32x4 acc[2][2];
    #pragma unroll
    for (int mt = 0; mt < 2; ++mt)
        #pragma unroll
        for (int nt = 0; nt < 2; ++nt)
            acc[mt][nt] = (f32x4){0.f, 0.f, 0.f, 0.f};

    for (int tap = 0; tap < KK; ++tap) {
        int ty = tap / 3 - 1;
        int tx = tap % 3 - 1;

        // ---- sampling: wave fills rows wavei*4 .. wavei*4+3 ----
        int u[4][4];        // SGPR element offsets within batch image
        float wt[4][4];     // SGPR bilinear weights
        #pragma unroll
        for (int i = 0; i < 4; ++i) {
            int pimg = pimgb + wavei * 4 + i;              // scalar
            float oy = off[obase + pimg + (2 * tap) * 4096];      // s_load
            float ox = off[obase + pimg + (2 * tap + 1) * 4096];  // s_load
            float py = (float)((pimg >> 6) + ty) + oy;
            float px = (float)((pimg & 63) + tx) + ox;
            float fy = floorf(py), fx = floorf(px);
            int   y0 = (int)fy,    x0 = (int)fx;
            float wy1 = py - fy, wx1 = px - fx;
            float wy0 = 1.f - wy1, wx0 = 1.f - wx1;
            wy0 = ((unsigned)y0       < 64u) ? wy0 : 0.f;
            wy1 = ((unsigned)(y0 + 1) < 64u) ? wy1 : 0.f;
            wx0 = ((unsigned)x0       < 64u) ? wx0 : 0.f;
            wx1 = ((unsigned)(x0 + 1) < 64u) ? wx1 : 0.f;
            int yc0 = min(max(y0, 0), 63),     yc1 = min(max(y0 + 1, 0), 63);
            int xc0 = min(max(x0, 0), 63),     xc1 = min(max(x0 + 1, 0), 63);
            u[i][0] = sreadi((yc0 * 64 + xc0) * 256);
            u[i][1] = sreadi((yc0 * 64 + xc1) * 256);
            u[i][2] = sreadi((yc1 * 64 + xc0) * 256);
            u[i][3] = sreadi((yc1 * 64 + xc1) * 256);
            wt[i][0] = sread(wy0 * wx0); wt[i][1] = sread(wy0 * wx1);
            wt[i][2] = sread(wy1 * wx0); wt[i][3] = sread(wy1 * wx1);
        }
        // issue all 16 gathers back-to-back (L2-local after band swizzle)
        bf16x4 v[4][4];
        #pragma unroll
        for (int i = 0; i < 4; ++i)
            #pragma unroll
            for (int j = 0; j < 4; ++j)
                v[i][j] = *reinterpret_cast<const bf16x4*>(xt + base + (unsigned)u[i][j]);
        // blend + LDS write
        #pragma unroll
        for (int i = 0; i < 4; ++i) {
            float a0 = 0.f, a1 = 0.f, a2 = 0.f, a3 = 0.f;
            #pragma unroll
            for (int j = 0; j < 4; ++j) {
                float wgt = wt[i][j];
                a0 += wgt * (float)v[i][j][0];
                a1 += wgt * (float)v[i][j][1];
                a2 += wgt * (float)v[i][j][2];
                a3 += wgt * (float)v[i][j][3];
            }
            bf16x4 sv;
            sv[0] = (bf16)a0; sv[1] = (bf16)a1;
            sv[2] = (bf16)a2; sv[3] = (bf16)a3;
            *reinterpret_cast<bf16x4*>(&S[wavei * 4 + i][lane * 4]) = sv;
        }
        __syncthreads();

        // ---- GEMM over this tap's k=256: wave = M32 x N32 ----
        const bf16* sp0 = &S[l16][quad * 8];
        const bf16* sp1 = &S[16 + l16][quad * 8];
        const bf16* ap0 = wq + ((size_t)((2 * wavei) * KITERS + tap * 8) * 64 + lane) * 8;
        const bf16* ap1 = ap0 + (size_t)KITERS * 64 * 8;
        #pragma unroll
        for (int kki = 0; kki < 8; ++kki) {
            bf16x8 b0 = *reinterpret_cast<const bf16x8*>(sp0 + kki * 32);
            bf16x8 b1 = *reinterpret_cast<const bf16x8*>(sp1 + kki * 32);
            bf16x8 a0 = *reinterpret_cast<const bf16x8*>(ap0 + (size_t)kki * 512);
            bf16x8 a1 = *reinterpret_cast<const bf16x8*>(ap1 + (size_t)kki * 512);
            acc[0][0] = __builtin_amdgcn_mfma_f32_16x16x32_bf16(a0, b0, acc[0][0], 0, 0, 0);
            acc[0][1] = __builtin_amdgcn_mfma_f32_16x16x32_bf16(a0, b1, acc[0][1], 0, 0, 0);
            acc[1][0] = __builtin_amdgcn_mfma_f32_16x16x32_bf16(a1, b0, acc[1][0], 0, 0, 0);
            acc[1][1] = __builtin_amdgcn_mfma_f32_16x16x32_bf16(a1, b1, acc[1][1], 0, 0, 0);
        }
        __syncthreads();   // S reused next tap
    }

    // ---- epilogue: C/D layout col=l16, row=quad*4+r ----
    #pragma unroll
    for (int nt = 0; nt < 2; ++nt) {
        int pg   = pix0 + nt * 16 + l16;
        int bb   = pg >> 12;
        int pimg = pg & 4095;
        #pragma unroll
        for (int mt = 0; mt < 2; ++mt) {
            int m = (2 * wavei + mt) * 16 + quad * 4;
            float* op = out + ((size_t)(bb * 256 + m)) * 4096 + pimg;
            #pragma unroll
            for (int r = 0; r < 4; ++r)
                op[(size_t)r * 4096] = acc[mt][nt][r] + bias[m + r];
        }
    }
}

// ---------------------------------------------------------------------------
extern "C" void kernel_launch(void* const* d_in, const int* in_sizes, int n_in,
                              void* d_out, int out_size, void* d_ws, size_t ws_size,
                              hipStream_t stream) {
    const float* x    = (const float*)d_in[0];   // [4,256,64,64]
    const float* off  = (const float*)d_in[1];   // [4,18,64,64]
    const float* w    = (const float*)d_in[2];   // [256,256,3,3]
    const float* bias = (const float*)d_in[3];   // [256]
    float* out = (float*)d_out;                  // [4,256,64,64]

    bf16* wq = (bf16*)d_ws;                               // 1,179,648 B
    bf16* xt = (bf16*)((char*)d_ws + (size_t)589824 * 2); // 8,388,608 B

    prep_k<<<3328, 256, 0, stream>>>(x, w, xt, wq);
    deform_gemm_k<<<512, 512, 0, stream>>>(xt, off, wq, bias, out);
}